// Round 1
// baseline (87.743 us; speedup 1.0000x reference)
//
#include <hip/hip_runtime.h>

namespace {
constexpr int L_LEN  = 4096;   // sequence length
constexpr int NTAPS  = 128;    // truncated filter length
constexpr int TPB    = 256;    // threads per block
constexpr int PT     = 16;     // outputs per thread (TPB*PT == L_LEN)
constexpr int NH     = 768;    // heads/channels
constexpr int KSTRIDE = 4096;  // k row stride (full row, only first 128 used)
constexpr int XPAD   = NTAPS;              // left zero pad so causal edge needs no branches
constexpr int XLEN   = XPAD + L_LEN;       // 4224
constexpr int SKLEN  = XLEN + (XLEN >> 4); // skewed length: 4488 floats (~17.5 KB)

// Skew: +1 word per 16 -> lane stride becomes 17 (odd) -> conflict-free scalar reads.
__device__ __forceinline__ int sk(int j) { return j + (j >> 4); }
} // namespace

__global__ __launch_bounds__(TPB) void PartialFFTConv_kernel(
    const float* __restrict__ x, const float* __restrict__ kf, float* __restrict__ y) {
    __shared__ float sx[SKLEN];
    __shared__ float skt[NTAPS];

    const int row = blockIdx.x;           // 0..6143  (b*768 + h)
    const int h   = row % NH;
    const float* xr = x + (size_t)row * L_LEN;
    float*       yr = y + (size_t)row * L_LEN;
    const float* kr = kf + (size_t)h * KSTRIDE;

    const int tid = threadIdx.x;

    // zero the skewed left-pad region (skewed indices 0..sk(XPAD)-1 = 0..135, contiguous cover)
    if (tid < sk(XPAD)) sx[tid] = 0.0f;
    // stage filter taps (32 lanes x float4 = 128 floats)
    if (tid < NTAPS / 4) ((float4*)skt)[tid] = ((const float4*)kr)[tid];

    // stage x row: coalesced float4 global loads, skewed scalar LDS writes.
    // j is a multiple of 4 so j..j+3 share a 16-block -> sk(j)+n valid.
    #pragma unroll
    for (int s = 0; s < L_LEN / (TPB * 4); ++s) {   // 4 iterations
        const int q = tid + s * TPB;                // float4 index in row
        const float4 v = ((const float4*)xr)[q];
        const int p = sk(XPAD + q * 4);
        sx[p + 0] = v.x;
        sx[p + 1] = v.y;
        sx[p + 2] = v.z;
        sx[p + 3] = v.w;
    }
    __syncthreads();

    const int l0 = tid * PT;              // this thread's first output index
    float acc[PT];
    float w[PT];                          // circular window: x[l0 + m] lives in slot (m & 15)
    #pragma unroll
    for (int i = 0; i < PT; ++i) acc[i] = 0.0f;

    // init window w[i] = x[l0 + i]; XPAD+l0 is 16-aligned so sk(base)+i is exact
    const int base0 = sk(XPAD + l0);
    #pragma unroll
    for (int i = 0; i < PT; ++i) w[i] = sx[base0 + i];

    // per-chunk read base: j_start = XPAD + l0 - 16*tc - 1 (== 15 mod 16, so the 16
    // addresses of a chunk are pb, pb-1, ..., pb-15 — immediate offsets off one base)
    int pb = base0 - 2;                   // sk(XPAD + l0 - 1)
    const float4* kf4 = (const float4*)skt;

    for (int tc = 0; tc < NTAPS / PT; ++tc) {       // 8 chunks of 16 taps (runtime loop)
        float kv[PT];
        #pragma unroll
        for (int i = 0; i < PT / 4; ++i)
            ((float4*)kv)[i] = kf4[tc * 4 + i];     // uniform-address broadcast reads

        #pragma unroll
        for (int dt = 0; dt < PT; ++dt) {
            // t = tc*16 + dt; t == dt (mod 16) so all slot indices are compile-time.
            #pragma unroll
            for (int i = 0; i < PT; ++i)
                acc[i] = fmaf(kv[dt], w[(i - dt) & 15], acc[i]);
            // retire x[l0+15-t] (slot (15-dt)&15), load x[l0-t-1] into that slot
            w[(15 - dt) & 15] = sx[pb - dt];
        }
        pb -= 17;                                   // next chunk: j drops 16 -> p drops 17
    }

    // store 16 consecutive outputs as 4 float4s (16B/lane, 64B-aligned bases)
    #pragma unroll
    for (int i = 0; i < PT / 4; ++i)
        ((float4*)(yr + l0))[i] =
            make_float4(acc[4 * i + 0], acc[4 * i + 1], acc[4 * i + 2], acc[4 * i + 3]);
}

extern "C" void kernel_launch(void* const* d_in, const int* in_sizes, int n_in,
                              void* d_out, int out_size, void* d_ws, size_t ws_size,
                              hipStream_t stream) {
    const float* x = (const float*)d_in[0];   // [8, 768, 4096] f32
    const float* k = (const float*)d_in[1];   // [768, 4096] f32 (first 128 taps used)
    float* y = (float*)d_out;                 // [8, 768, 4096] f32
    const int rows = in_sizes[0] / L_LEN;     // 6144
    hipLaunchKernelGGL(PartialFFTConv_kernel, dim3(rows), dim3(TPB), 0, stream, x, k, y);
}

// Round 2
// 36.972 us; speedup vs baseline: 2.3732x; 2.3732x over previous
//
#include <hip/hip_runtime.h>

namespace {
constexpr int L_LEN   = 4096;   // sequence length
constexpr int NTAPS   = 128;    // truncated filter length
constexpr int NH      = 768;    // heads
constexpr int KSTRIDE = 4096;   // k row stride
constexpr int TPB     = 256;    // 4 waves
constexpr int PADB    = 160;    // left zero pad in bf16 elems (10 blocks of 16)
constexpr int XB      = PADB + L_LEN;  // 4256 bf16 staged per row
constexpr int NP      = 5;      // K-pairs: q = (0,1),(2,3),(4,5),(6,7),(8,9-zero)

typedef __attribute__((ext_vector_type(8))) short  short8;  // 8 bf16 (4 VGPRs)
typedef __attribute__((ext_vector_type(4))) float  f32x4;   // MFMA accumulator

// XOR-swizzle: flip byte-bit4 by byte-bit7 -> spreads 32B-strided b128 reads across banks.
// 16B-aligned blocks stay contiguous (only bit4 flips, blocks never straddle 128B).
__device__ __forceinline__ unsigned swz(unsigned byte) {
    return byte ^ (((byte >> 7) & 1u) << 4);
}
// fp32 -> bf16 round-to-nearest-even
__device__ __forceinline__ unsigned short f2bf(float f) {
    unsigned u = __builtin_bit_cast(unsigned, f);
    u += 0x7FFFu + ((u >> 16) & 1u);
    return (unsigned short)(u >> 16);
}
} // namespace

__global__ __launch_bounds__(TPB) void pconv_mfma(
    const float* __restrict__ x, const float* __restrict__ kf, float* __restrict__ y) {
    __shared__ float         skf[NTAPS];      // filter taps, f32
    __shared__ unsigned char sxb[XB * 2];     // x row as bf16, swizzled

    const int tid = threadIdx.x;
    const int row = blockIdx.x;               // b*768 + h
    const int h   = row % NH;

    // ---- stage filter (f32, 128 taps) ----
    if (tid < NTAPS / 4)
        ((float4*)skf)[tid] = ((const float4*)(kf + (size_t)h * KSTRIDE))[tid];

    // ---- zero left pad: 320 bytes as 40 x 8B ----
    if (tid < PADB / 4)
        *(unsigned long long*)(sxb + swz(8u * tid)) = 0ull;

    // ---- stage x row: coalesced float4 loads -> bf16 -> swizzled 8B LDS writes ----
    const float* xr = x + (size_t)row * L_LEN;
    #pragma unroll
    for (int s = 0; s < L_LEN / (TPB * 4); ++s) {           // 4 iters
        const int q4 = tid + s * TPB;
        const float4 v = ((const float4*)xr)[q4];
        unsigned long long pk =
            (unsigned long long)f2bf(v.x)
          | ((unsigned long long)f2bf(v.y) << 16)
          | ((unsigned long long)f2bf(v.z) << 32)
          | ((unsigned long long)f2bf(v.w) << 48);
        *(unsigned long long*)(sxb + swz(2u * PADB + 8u * q4)) = pk;
    }
    __syncthreads();

    // ---- build Toeplitz A fragments (shared across waves; once per block) ----
    // A[i][kk] = k[t], t = 16*q + i - j;  kk = 8*g + e, q = 2p + (g>>1), j = 8*(g&1) + e
    const int lane = tid & 63;
    const int i    = lane & 15;               // M row (and N col for B/D)
    const int g    = lane >> 4;               // k-group 0..3
    short8 afrag[NP];
    #pragma unroll
    for (int p = 0; p < NP; ++p) {
        const int tbase = 32 * p + 16 * (g >> 1) + i - 8 * (g & 1);
        short8 a;
        #pragma unroll
        for (int e = 0; e < 8; ++e) {
            const int t = tbase - e;
            const float kv = (t >= 0 && t < NTAPS) ? skf[t] : 0.0f;
            a[e] = (short)f2bf(kv);
        }
        afrag[p] = a;
    }

    // ---- 4 tiles per wave: C[16 i x 16 n] over 16 consecutive m-blocks ----
    const int wave = tid >> 6;
    float* yr = y + (size_t)row * L_LEN;
    #pragma unroll
    for (int tt = 0; tt < 4; ++tt) {
        const int m0 = (wave * 4 + tt) * 16;  // first m-block of this tile
        f32x4 acc = {0.f, 0.f, 0.f, 0.f};
        #pragma unroll
        for (int p = 0; p < NP; ++p) {
            // B[kk][n] = x_pad[16*(m0 + n - 2p - (g>>1)) + 8*(g&1) + e], n = i
            const unsigned raw = 32u * (unsigned)(10 + m0 + i - 2 * p - (g >> 1))
                               + 16u * (unsigned)(g & 1);
            const short8 b = *(const short8*)(sxb + swz(raw));
            acc = __builtin_amdgcn_mfma_f32_16x16x32_bf16(afrag[p], b, acc, 0, 0, 0);
        }
        // C layout: col n = lane&15 (= i), row = 4*g + r  ->  y[16*(m0+n) + 4g + r]
        *(f32x4*)(yr + 16 * (m0 + i) + 4 * g) = acc;
    }
}

extern "C" void kernel_launch(void* const* d_in, const int* in_sizes, int n_in,
                              void* d_out, int out_size, void* d_ws, size_t ws_size,
                              hipStream_t stream) {
    const float* x = (const float*)d_in[0];   // [8, 768, 4096] f32
    const float* k = (const float*)d_in[1];   // [768, 4096] f32 (first 128 taps used)
    float* y = (float*)d_out;                 // [8, 768, 4096] f32
    const int rows = in_sizes[0] / L_LEN;     // 6144
    hipLaunchKernelGGL(pconv_mfma, dim3(rows), dim3(TPB), 0, stream, x, k, y);
}

// Round 5
// 35.279 us; speedup vs baseline: 2.4871x; 1.0480x over previous
//
#include <hip/hip_runtime.h>

namespace {
constexpr int L_LEN   = 4096;   // sequence length
constexpr int NTAPS   = 128;    // truncated filter length
constexpr int NH      = 768;    // heads
constexpr int KSTRIDE = 4096;   // k row stride
constexpr int TPB     = 256;    // 4 waves
constexpr int PADB    = 160;    // left zero pad in bf16 elems (10 blocks of 16)
constexpr int XB      = PADB + L_LEN;  // 4256 bf16 staged per row
constexpr int NP      = 5;      // K-pairs: q = (0,1),(2,3),(4,5),(6,7),(8,9-zero)

typedef __attribute__((ext_vector_type(8))) short  short8;  // 8 bf16 (4 VGPRs)
typedef __attribute__((ext_vector_type(4))) float  f32x4;   // MFMA accumulator

// XOR-swizzle: flip byte-bit4 by byte-bit7 -> spreads 32B-strided b128 reads across banks.
__device__ __forceinline__ unsigned swz(unsigned byte) {
    return byte ^ (((byte >> 7) & 1u) << 4);
}
// fp32 -> bf16 round-to-nearest-even (proven in rounds 1-2)
__device__ __forceinline__ unsigned short f2bf(float f) {
    unsigned u = __builtin_bit_cast(unsigned, f);
    u += 0x7FFFu + ((u >> 16) & 1u);
    return (unsigned short)(u >> 16);
}
} // namespace

__global__ __launch_bounds__(TPB) void pconv_mfma(
    const float* __restrict__ x, const float* __restrict__ kf, float* __restrict__ y) {
    __shared__ float         skf[NTAPS];      // filter taps, f32
    __shared__ unsigned char sxb[XB * 2];     // x row as bf16, swizzled

    const int tid = threadIdx.x;
    const int row = blockIdx.x;               // b*768 + h
    const int h   = row % NH;

    // ---- stage filter (f32, 128 taps) ----
    if (tid < NTAPS / 4)
        ((float4*)skf)[tid] = ((const float4*)(kf + (size_t)h * KSTRIDE))[tid];

    // ---- zero left pad: 320 bytes as 40 x 8B ----
    if (tid < PADB / 4)
        *(unsigned long long*)(sxb + swz(8u * tid)) = 0ull;

    // ---- stage x row: coalesced float4 loads -> bf16 -> swizzled 8B LDS writes ----
    const float* xr = x + (size_t)row * L_LEN;
    #pragma unroll
    for (int s = 0; s < L_LEN / (TPB * 4); ++s) {           // 4 iters
        const int q4 = tid + s * TPB;
        const float4 v = ((const float4*)xr)[q4];
        unsigned long long pk =
            (unsigned long long)f2bf(v.x)
          | ((unsigned long long)f2bf(v.y) << 16)
          | ((unsigned long long)f2bf(v.z) << 32)
          | ((unsigned long long)f2bf(v.w) << 48);
        *(unsigned long long*)(sxb + swz(2u * PADB + 8u * q4)) = pk;
    }
    __syncthreads();

    // ---- build Toeplitz A fragments (once per block) ----
    // A[i][kk] = k[t], t = 16*q + i - j;  kk = 8*g + e, q = 2p + (g>>1), j = 8*(g&1) + e
    const int lane = tid & 63;
    const int i    = lane & 15;               // M row (and N col for B/D)
    const int g    = lane >> 4;               // k-group 0..3
    short8 afrag[NP];
    #pragma unroll
    for (int p = 0; p < NP; ++p) {
        const int tbase = 32 * p + 16 * (g >> 1) + i - 8 * (g & 1);
        short8 a;
        #pragma unroll
        for (int e = 0; e < 8; ++e) {
            const int t = tbase - e;
            const float kv = (t >= 0 && t < NTAPS) ? skf[t] : 0.0f;
            a[e] = (short)f2bf(kv);
        }
        afrag[p] = a;
    }

    // ---- 4 tiles per wave: C[16 i x 16 n] over 16 consecutive m-blocks ----
    const int wave = tid >> 6;
    float* yr = y + (size_t)row * L_LEN;
    #pragma unroll
    for (int tt = 0; tt < 4; ++tt) {
        const int m0 = (wave * 4 + tt) * 16;  // first m-block of this tile
        f32x4 acc = {0.f, 0.f, 0.f, 0.f};
        #pragma unroll
        for (int p = 0; p < NP; ++p) {
            // B[kk][n] = x_pad[16*(m0 + n - 2p - (g>>1)) + 8*(g&1) + e], n = i
            const unsigned raw = 32u * (unsigned)(10 + m0 + i - 2 * p - (g >> 1))
                               + 16u * (unsigned)(g & 1);
            const short8 b = *(const short8*)(sxb + swz(raw));
            acc = __builtin_amdgcn_mfma_f32_16x16x32_bf16(afrag[p], b, acc, 0, 0, 0);
        }
        // C layout: col n = lane&15 (= i), row = 4*g + r  ->  y[16*(m0+n) + 4g + r].
        // The wave's 64 lanes cover a contiguous 1 KB span (lane-permuted) -> already
        // fully coalesced. nt: y is write-once, never re-read -> don't thrash L2/L3
        // (keep x resident instead).
        __builtin_nontemporal_store(acc, (f32x4*)(yr + 16 * (m0 + i) + 4 * g));
    }
}

extern "C" void kernel_launch(void* const* d_in, const int* in_sizes, int n_in,
                              void* d_out, int out_size, void* d_ws, size_t ws_size,
                              hipStream_t stream) {
    const float* x = (const float*)d_in[0];   // [8, 768, 4096] f32
    const float* k = (const float*)d_in[1];   // [768, 4096] f32 (first 128 taps used)
    float* y = (float*)d_out;                 // [8, 768, 4096] f32
    const int rows = in_sizes[0] / L_LEN;     // 6144
    hipLaunchKernelGGL(pconv_mfma, dim3(rows), dim3(TPB), 0, stream, x, k, y);
}